// Round 13
// baseline (630.562 us; speedup 1.0000x reference)
//
#include <hip/hip_runtime.h>
#include <cstdint>

#define NND 5000
#define NE 160000
#define NF 128
#define NH 256
#define NT 10
#define MT 10
#define NC 8
#define NMAT (NND*MT)      // G: unpadded stride 10 (sinkhorn-friendly)
#define ROWP 12            // T/M: padded row stride (48 B, float4-aligned gathers)
#define NMATP (NND*ROWP)
#define CG_ITERS 5
#define SINK_IT 30
#define SKB 1024           // sinkhorn block size (16 waves = 4/SIMD)
#define SKR 5              // rows per sinkhorn thread (5*1024 >= 5000)

// ---------------- wave-level f32 reductions (DPP, VALU pipe) ----------------
#if __has_builtin(__builtin_amdgcn_update_dpp)
#define DPP_ADD(x, ctrl, rmask) \
    ((x) + __int_as_float(__builtin_amdgcn_update_dpp(0, __float_as_int(x), (ctrl), (rmask), 0xf, true)))
#define DPP_MAX(x, ctrl, rmask) \
    fmaxf((x), __int_as_float(__builtin_amdgcn_update_dpp(0, __float_as_int(x), (ctrl), (rmask), 0xf, true)))
__device__ __forceinline__ float wave_sum63(float x) {
    x = DPP_ADD(x, 0x111, 0xf);   // row_shr:1
    x = DPP_ADD(x, 0x112, 0xf);   // row_shr:2
    x = DPP_ADD(x, 0x114, 0xf);   // row_shr:4
    x = DPP_ADD(x, 0x118, 0xf);   // row_shr:8
    x = DPP_ADD(x, 0x142, 0xa);   // row_bcast:15 -> rows 1,3
    x = DPP_ADD(x, 0x143, 0xc);   // row_bcast:31 -> rows 2,3
    return x;                      // lane 63 = full 64-lane sum
}
// valid for x >= 0 (identity 0 from bound_ctrl)
__device__ __forceinline__ float wave_max63(float x) {
    x = DPP_MAX(x, 0x111, 0xf);
    x = DPP_MAX(x, 0x112, 0xf);
    x = DPP_MAX(x, 0x114, 0xf);
    x = DPP_MAX(x, 0x118, 0xf);
    x = DPP_MAX(x, 0x142, 0xa);
    x = DPP_MAX(x, 0x143, 0xc);
    return x;
}
#else
__device__ __forceinline__ float wave_sum63(float x) {
#pragma unroll
    for (int off = 32; off; off >>= 1) x += __shfl_xor(x, off);
    return x;
}
__device__ __forceinline__ float wave_max63(float x) {
#pragma unroll
    for (int off = 32; off; off >>= 1) x = fmaxf(x, __shfl_xor(x, off));
    return x;
}
#endif

__device__ __forceinline__ float frcp(float x) {
#if __has_builtin(__builtin_amdgcn_rcpf)
    return __builtin_amdgcn_rcpf(x);   // v_rcp_f32, ~1 ulp
#else
    return 1.f / x;
#endif
}

// ---------------- graph prep (merged) ----------------

__global__ void k_edge1(const int* __restrict__ src, const int* __restrict__ dst,
                        int* __restrict__ cntD, unsigned* __restrict__ bitmap,
                        int* __restrict__ cntS, unsigned char* __restrict__ keep) {
    for (int e = blockIdx.x*blockDim.x + threadIdx.x; e < NE; e += gridDim.x*blockDim.x) {
        int s = src[e], d = dst[e];
        atomicAdd(&cntD[d], 1);
        int key = s * NND + d;
        unsigned bit = 1u << (key & 31);
        unsigned old = atomicOr(&bitmap[key >> 5], bit);
        if (!(old & bit)) { keep[e] = 1; atomicAdd(&cntS[s], 1); }
        else keep[e] = 0;
    }
}

// block 0: cntD -> rpD (+ dinv); block 1: cntS -> rpS (+ c1row);
// block 2: c2row + template row sums (for closed-form first gradient)
__global__ void k_exscan2(const int* __restrict__ cntD, int* __restrict__ rpD,
                          float* __restrict__ dinv,
                          const int* __restrict__ cntS, int* __restrict__ rpS,
                          float* __restrict__ c1row,
                          const float* __restrict__ tpl, float* __restrict__ c2row,
                          float* __restrict__ rsT) {
    const int T = 1024;
    int tid = threadIdx.x;
    if (blockIdx.x == 2) {
        if (tid < NT * MT) {
            int t = tid / MT, j = tid % MT;
            float s = 0.f, rs = 0.f;
            for (int k = 0; k < MT; k++) {
                float v = tpl[t * 100 + j * 10 + k];
                s += v * v; rs += v;
            }
            c2row[tid] = s * (1.f / MT);
            rsT[tid] = rs;
        }
        return;
    }
    const int* cnt = blockIdx.x ? cntS : cntD;
    int* rp = blockIdx.x ? rpS : rpD;
    int C = (NND + T - 1) / T;
    int begin = tid * C, end = begin + C; if (end > NND) end = NND; if (begin > NND) begin = NND;
    int s = 0;
    for (int i = begin; i < end; i++) s += cnt[i];
    __shared__ int part[1024];
    part[tid] = s; __syncthreads();
    for (int off = 1; off < T; off <<= 1) {
        int v = (tid >= off) ? part[tid - off] : 0;
        __syncthreads();
        part[tid] += v;
        __syncthreads();
    }
    int run = part[tid] - s;   // exclusive
    for (int i = begin; i < end; i++) { rp[i] = run; run += cnt[i]; }
    if (tid == T - 1) rp[NND] = part[T - 1];
    if (blockIdx.x == 0)
        for (int i = begin; i < end; i++) dinv[i] = rsqrtf((float)(cnt[i] + 1));
    else
        for (int i = begin; i < end; i++) c1row[i] = (float)cnt[i] * (1.f / NND);
}

__global__ void k_scatter2(const int* __restrict__ src, const int* __restrict__ dst,
                           const unsigned char* __restrict__ keep,
                           const int* __restrict__ rpD, int* __restrict__ cur1,
                           int* __restrict__ csrS, float* __restrict__ csrC,
                           const float* __restrict__ dinv,
                           const int* __restrict__ rpS, int* __restrict__ cur2,
                           int* __restrict__ csrD) {
    for (int e = blockIdx.x*blockDim.x + threadIdx.x; e < NE; e += gridDim.x*blockDim.x) {
        int s = src[e], d = dst[e];
        int pos = rpD[d] + atomicAdd(&cur1[d], 1);
        csrS[pos] = s;
        csrC[pos] = dinv[s] * dinv[d];
        if (keep[e]) {
            int p2 = rpS[s] + atomicAdd(&cur2[s], 1);
            csrD[p2] = d;
        }
    }
}

// ---------------- GCN ----------------
// GCN layer = agg(x @ W) + b; aggregation is linear in features, so layer 1
// uses (agg x) @ W + b (aggregate 128-dim rows instead of 256-dim).

__global__ __launch_bounds__(256) void k_gemm(const float* __restrict__ A,
                                              const float* __restrict__ B,
                                              float* __restrict__ C, int M, int N, int K,
                                              const float* __restrict__ bias, int relu) {
    const int BM = 64, BN = 64, BK = 32;   // BK=32: half the barriers of BK=16
    __shared__ float As[BK][BM + 4];       // rows 272B, 16B-aligned
    __shared__ float Bs[BK][BN];
    int tid = threadIdx.x;
    int row0 = blockIdx.y * BM, col0 = blockIdx.x * BN;
    int tx = tid % 16, ty = tid / 16;
    float acc[4][4] = {};
    for (int k0 = 0; k0 < K; k0 += BK) {
#pragma unroll
        for (int l = 0; l < 8; l++) {
            int idx = tid + l * 256;
            int r = idx / BK, kk = idx % BK;
            int gr = row0 + r;
            As[kk][r] = (gr < M) ? A[(size_t)gr * K + k0 + kk] : 0.f;
        }
#pragma unroll
        for (int l = 0; l < 8; l++) {
            int idx = tid + l * 256;
            int kk = idx / BN, c = idx % BN;
            Bs[kk][c] = B[(size_t)(k0 + kk) * N + col0 + c];
        }
        __syncthreads();
#pragma unroll
        for (int kk = 0; kk < BK; kk++) {
            float a[4], b[4];
#pragma unroll
            for (int i = 0; i < 4; i++) a[i] = As[kk][ty * 4 + i];
#pragma unroll
            for (int j = 0; j < 4; j++) b[j] = Bs[kk][tx * 4 + j];
#pragma unroll
            for (int i = 0; i < 4; i++)
#pragma unroll
                for (int j = 0; j < 4; j++) acc[i][j] += a[i] * b[j];
        }
        __syncthreads();
    }
#pragma unroll
    for (int i = 0; i < 4; i++) {
        int gr = row0 + ty * 4 + i;
        if (gr < M) {
#pragma unroll
            for (int j = 0; j < 4; j++) {
                int gc = col0 + tx * 4 + j;
                float o = acc[i][j];
                if (bias) o += bias[gc];
                if (relu) o = fmaxf(o, 0.f);
                C[(size_t)gr * N + gc] = o;
            }
        }
    }
}

// layer-1 aggregation over 128-dim rows: 8 nodes/256-block, 32 lanes x float4
// 4-way unrolled edge loop (four independent gather chains)
__global__ __launch_bounds__(256) void k_aggregate(const float4* __restrict__ hin4,
                            float4* __restrict__ hout4, const int* __restrict__ rp,
                            const int* __restrict__ csrS, const float* __restrict__ csrC,
                            const float* __restrict__ dinv) {
    int v = blockIdx.x * 8 + (threadIdx.x >> 5);
    int l = threadIdx.x & 31;
    float dv = dinv[v];
    float sc = dv * dv;
    float4 a = hin4[(size_t)v * 32 + l];
    float4 acc = make_float4(a.x * sc, a.y * sc, a.z * sc, a.w * sc);
    int e0 = rp[v], e1 = rp[v + 1];
    int e = e0;
    for (; e + 3 < e1; e += 4) {
        int s0 = csrS[e],   s1 = csrS[e+1], s2 = csrS[e+2], s3 = csrS[e+3];
        float c0 = csrC[e], c1 = csrC[e+1], c2 = csrC[e+2], c3 = csrC[e+3];
        float4 h0 = hin4[(size_t)s0 * 32 + l];
        float4 h1 = hin4[(size_t)s1 * 32 + l];
        float4 h2 = hin4[(size_t)s2 * 32 + l];
        float4 h3 = hin4[(size_t)s3 * 32 + l];
        acc.x = fmaf(h0.x, c0, acc.x); acc.y = fmaf(h0.y, c0, acc.y);
        acc.z = fmaf(h0.z, c0, acc.z); acc.w = fmaf(h0.w, c0, acc.w);
        acc.x = fmaf(h1.x, c1, acc.x); acc.y = fmaf(h1.y, c1, acc.y);
        acc.z = fmaf(h1.z, c1, acc.z); acc.w = fmaf(h1.w, c1, acc.w);
        acc.x = fmaf(h2.x, c2, acc.x); acc.y = fmaf(h2.y, c2, acc.y);
        acc.z = fmaf(h2.z, c2, acc.z); acc.w = fmaf(h2.w, c2, acc.w);
        acc.x = fmaf(h3.x, c3, acc.x); acc.y = fmaf(h3.y, c3, acc.y);
        acc.z = fmaf(h3.z, c3, acc.z); acc.w = fmaf(h3.w, c3, acc.w);
    }
    for (; e < e1; e++) {
        int s0 = csrS[e]; float c0 = csrC[e];
        float4 h0 = hin4[(size_t)s0 * 32 + l];
        acc.x = fmaf(h0.x, c0, acc.x); acc.y = fmaf(h0.y, c0, acc.y);
        acc.z = fmaf(h0.z, c0, acc.z); acc.w = fmaf(h0.w, c0, acc.w);
    }
    hout4[(size_t)v * 32 + l] = acc;
}

// ---------------- fused: aggregate2 + M + T-init + closed-form grad0 ----------------
// One block per node (128 threads). Aggregation: 4 edge-quads x 32 lanes x float4
// (16B/lane coalesced, 4 independent chains), LDS-combine of partial rows.
// h2 row stays in LDS; M/T padded, G unpadded.
__global__ __launch_bounds__(128) void k_fuse(const float* __restrict__ t2,
                    const float* __restrict__ b2,
                    const int* __restrict__ rp, const int* __restrict__ csrS,
                    const float* __restrict__ csrC, const float* __restrict__ dinv,
                    const float* __restrict__ tplF,
                    const float* __restrict__ c1row, const int* __restrict__ cntS,
                    const float* __restrict__ c2row, const float* __restrict__ rsT,
                    float* __restrict__ Mm, float* __restrict__ G,
                    float* __restrict__ T, float* __restrict__ pmax) {
    int i = blockIdx.x;
    int tid = threadIdx.x;
    int lane = tid & 63, w = tid >> 6;
    int q = tid >> 5, l = tid & 31;          // edge-quad, feature-f4 lane
    __shared__ float4 sacc[4][32];
    __shared__ float hrow[NF];
    __shared__ float part[2];
    __shared__ float sMax[112];
    const float4* t24 = (const float4*)t2;
    // phase 1: gather neighbor rows, 4 edges in parallel (q = edge slot)
    float4 f = make_float4(0.f, 0.f, 0.f, 0.f);
    int e0 = rp[i], e1 = rp[i + 1];
    for (int e = e0 + q; e < e1; e += 4) {
        int s = csrS[e];
        float c = csrC[e];
        float4 h = t24[(size_t)s * 32 + l];
        f.x = fmaf(h.x, c, f.x); f.y = fmaf(h.y, c, f.y);
        f.z = fmaf(h.z, c, f.z); f.w = fmaf(h.w, c, f.w);
    }
    sacc[q][l] = f;
    __syncthreads();
    // phase 2: combine quads + self-loop + bias -> hrow (32 lanes)
    if (tid < 32) {
        float4 r0 = sacc[0][tid], r1 = sacc[1][tid], r2 = sacc[2][tid], r3 = sacc[3][tid];
        float dv = dinv[i];
        float sc = dv * dv;
        float4 sv = t24[(size_t)i * 32 + tid];
        float4 bb = ((const float4*)b2)[tid];
        float4 o;
        o.x = (r0.x + r1.x) + (r2.x + r3.x) + sv.x * sc + bb.x;
        o.y = (r0.y + r1.y) + (r2.y + r3.y) + sv.y * sc + bb.y;
        o.z = (r0.z + r1.z) + (r2.z + r3.z) + sv.z * sc + bb.z;
        o.w = (r0.w + r1.w) + (r2.w + r3.w) + sv.w * sc + bb.w;
        ((float4*)hrow)[tid] = o;
    }
    __syncthreads();
    float hv = hrow[tid];
    float ps = wave_sum63(hv * hv);
    if (lane == 63) part[w] = ps;
    __syncthreads();
    float sx = part[0] + part[1];
    int c = tid;
    if (c < NT * MT) {
        const float4* Fc = (const float4*)(tplF + (size_t)c * NF);
        const float4* hr = (const float4*)hrow;
        float dot = 0.f, nrm = 0.f;
#pragma unroll 8
        for (int ff = 0; ff < NF / 4; ff++) {
            float4 fv = Fc[ff];
            float4 hq = hr[ff];
            dot = fmaf(hq.x, fv.x, dot); dot = fmaf(hq.y, fv.y, dot);
            dot = fmaf(hq.z, fv.z, dot); dot = fmaf(hq.w, fv.w, dot);
            nrm = fmaf(fv.x, fv.x, nrm); nrm = fmaf(fv.y, fv.y, nrm);
            nrm = fmaf(fv.z, fv.z, nrm); nrm = fmaf(fv.w, fv.w, nrm);
        }
        float m = sx + nrm - 2.f * dot;
        int t = c / MT, j = c % MT;
        size_t baseP = (size_t)t * NMATP + (size_t)i * ROWP + j;   // padded (M, T)
        Mm[baseP] = m;
        T[baseP] = 1.f / (float)NMAT;
        // closed-form first gradient (T0 uniform) -> unpadded G
        float g = 0.5f * m + c1row[i] + c2row[c]
                - ((float)cntS[i] * (1.f / NMAT)) * (2.f * rsT[c]);
        G[(size_t)t * NMAT + (size_t)i * MT + j] = g;
        sMax[c] = fabsf(g);
    }
    __syncthreads();
    if (tid < NT) {
        float m = sMax[tid * 10];
#pragma unroll
        for (int k = 1; k < 10; k++) m = fmaxf(m, sMax[tid * 10 + k]);
        pmax[(size_t)tid * NND + i] = m;
    }
}

// ---------------- CG gradient (t >= 1) — padded T gather (4-way), unpadded G write ----------------

__global__ __launch_bounds__(256) void k_grad(const float* __restrict__ T, const float* __restrict__ Mm,
                                              const float* __restrict__ c1row, const float* __restrict__ c2row,
                                              const float* __restrict__ tpl,
                                              const int* __restrict__ rpS, const int* __restrict__ csrD,
                                              float* __restrict__ G, unsigned* __restrict__ scaleBits) {
    int t = blockIdx.y;
    int tid = threadIdx.x;
    __shared__ float tC2[100];
    if (tid < 100) tC2[tid] = 2.f * tpl[t * 100 + tid];
    __syncthreads();
    int i = blockIdx.x * 256 + tid;
    float amax = 0.f;
    if (i < NND) {
        const float* Tt = T + (size_t)t * NMATP;
        float4 A0 = make_float4(0.f,0.f,0.f,0.f);
        float4 A1 = make_float4(0.f,0.f,0.f,0.f);
        float2 A2 = make_float2(0.f,0.f);
        int e0 = rpS[i], e1 = rpS[i + 1];
        int e = e0;
        for (; e + 3 < e1; e += 4) {   // four independent gather chains
            int ka = csrD[e], kb = csrD[e+1], kc = csrD[e+2], kd = csrD[e+3];
            const float4* Ta = (const float4*)(Tt + (size_t)ka * ROWP);
            const float4* Tb = (const float4*)(Tt + (size_t)kb * ROWP);
            const float4* Tc = (const float4*)(Tt + (size_t)kc * ROWP);
            const float4* Td = (const float4*)(Tt + (size_t)kd * ROWP);
            float4 a0 = Ta[0], a1 = Ta[1]; float2 a2 = ((const float2*)Ta)[4];
            float4 b0 = Tb[0], b1 = Tb[1]; float2 b2v = ((const float2*)Tb)[4];
            float4 c0 = Tc[0], c1 = Tc[1]; float2 c2v = ((const float2*)Tc)[4];
            float4 d0 = Td[0], d1 = Td[1]; float2 d2v = ((const float2*)Td)[4];
            A0.x += (a0.x + b0.x) + (c0.x + d0.x);
            A0.y += (a0.y + b0.y) + (c0.y + d0.y);
            A0.z += (a0.z + b0.z) + (c0.z + d0.z);
            A0.w += (a0.w + b0.w) + (c0.w + d0.w);
            A1.x += (a1.x + b1.x) + (c1.x + d1.x);
            A1.y += (a1.y + b1.y) + (c1.y + d1.y);
            A1.z += (a1.z + b1.z) + (c1.z + d1.z);
            A1.w += (a1.w + b1.w) + (c1.w + d1.w);
            A2.x += (a2.x + b2v.x) + (c2v.x + d2v.x);
            A2.y += (a2.y + b2v.y) + (c2v.y + d2v.y);
        }
        for (; e < e1; e++) {
            int ka = csrD[e];
            const float4* Ta = (const float4*)(Tt + (size_t)ka * ROWP);
            float4 a0 = Ta[0], a1 = Ta[1];
            float2 a2 = ((const float2*)Ta)[4];
            A0.x += a0.x; A0.y += a0.y; A0.z += a0.z; A0.w += a0.w;
            A1.x += a1.x; A1.y += a1.y; A1.z += a1.z; A1.w += a1.w;
            A2.x += a2.x; A2.y += a2.y;
        }
        float L[10] = {A0.x, A0.y, A0.z, A0.w, A1.x, A1.y, A1.z, A1.w, A2.x, A2.y};
        const float4* Mt4 = (const float4*)(Mm + (size_t)t * NMATP + (size_t)i * ROWP);
        float4 m0 = Mt4[0], m1 = Mt4[1];
        float2 m2 = ((const float2*)Mt4)[4];
        float m[10] = {m0.x, m0.y, m0.z, m0.w, m1.x, m1.y, m1.z, m1.w, m2.x, m2.y};
        float c1 = c1row[i];
        float g[10];
#pragma unroll
        for (int j = 0; j < MT; j++) {
            float s = 0.f;
#pragma unroll
            for (int k = 0; k < MT; k++) s = fmaf(L[k], tC2[j * 10 + k], s);
            g[j] = 0.5f * m[j] + (c1 + c2row[t * 10 + j] - s);
            amax = fmaxf(amax, fabsf(g[j]));
        }
        float2* Gt2 = (float2*)(G + (size_t)t * NMAT + (size_t)i * MT);   // unpadded
#pragma unroll
        for (int h = 0; h < 5; h++) Gt2[h] = make_float2(g[2*h], g[2*h+1]);
    }
    __shared__ float red[256];
    red[tid] = amax; __syncthreads();
    for (int off = 128; off > 0; off >>= 1) {
        if (tid < off) red[tid] = fmaxf(red[tid], red[tid + off]);
        __syncthreads();
    }
    if (tid == 0) atomicMax(&scaleBits[t], __float_as_uint(red[0]));
}

// ---------------- sinkhorn ----------------
// 1024 threads (16 waves = 4/SIMD), 5 rows/thread. Round-12 postmortem: at 512
// threads only 2 waves/SIMD are resident — too few to hide the 10-deep FMA and
// 6-deep DPP dependency chains between barriers (measured 1.6 us/iter vs ~0.4
// ideal). flat_work_group_size(1024,1024)+waves_per_eu(4,4) => 128-VGPR budget;
// live set ~90 floats fits in ARCH VGPRs (round-6's AGPR-shuttle trap avoided).
__global__ __attribute__((amdgpu_flat_work_group_size(1024, 1024), amdgpu_waves_per_eu(4, 4)))
void k_sinkhorn(const float* __restrict__ G,
                const unsigned* __restrict__ scaleBits,
                const float* __restrict__ pmax,
                float* __restrict__ T, float step) {
    int t = blockIdx.x;
    int tid = threadIdx.x;
    int lane = tid & 63, w = tid >> 6;

    __shared__ float wred[16][10];
    __shared__ float4 vbc4[3];     // 12 floats, 16B-aligned for b128 broadcast reads
    __shared__ float scsh;

    float sc;
    if (pmax) {   // CG iter 0: reduce per-node maxes here (no atomics upstream)
        const float* pm = pmax + (size_t)t * NND;
        float m = 0.f;
        for (int k = tid; k < NND; k += SKB) m = fmaxf(m, pm[k]);
        m = wave_max63(m);
        if (lane == 63) wred[w][0] = m;
        __syncthreads();
        if (tid == 0) {
            float mm = wred[0][0];
#pragma unroll
            for (int q = 1; q < 16; q++) mm = fmaxf(mm, wred[q][0]);
            scsh = mm;
        }
        __syncthreads();
        sc = scsh;
    } else {
        sc = __uint_as_float(scaleBits[t]);
    }
    float inv = -1.f / (0.02f * (sc + 1e-9f));
    const float* Gt = G + (size_t)t * NMAT;    // unpadded stride 10
    float* Tt = T + (size_t)t * NMATP;         // padded stride 12

    float Kf[SKR][10];
    float u[SKR];
#pragma unroll
    for (int r = 0; r < SKR; r++) {
        int i = tid + r * SKB;
        if (i < NND) {
            u[r] = 1.f;
            const float2* Gr = (const float2*)(Gt + (size_t)i * 10);
#pragma unroll
            for (int h = 0; h < 5; h++) {
                float2 g = Gr[h];
                Kf[r][2*h]   = __expf(g.x * inv);
                Kf[r][2*h+1] = __expf(g.y * inv);
            }
        } else {
            u[r] = 0.f;
#pragma unroll
            for (int j = 0; j < 10; j++) Kf[r][j] = 0.f;
        }
    }

    float vv[10];

    for (int it = 0; it < SINK_IT; it++) {
        // column partials over this thread's 5 rows
        float S[10];
#pragma unroll
        for (int j = 0; j < 10; j++) S[j] = 0.f;
#pragma unroll
        for (int r = 0; r < SKR; r++) {
            float ur = u[r];
#pragma unroll
            for (int j = 0; j < 10; j++) S[j] = fmaf(Kf[r][j], ur, S[j]);
        }
        // DPP wave reduction (result in lane 63), lane 63 publishes
#pragma unroll
        for (int j = 0; j < 10; j++) {
            float s = wave_sum63(S[j]);
            if (lane == 63) wred[w][j] = s;
        }
        __syncthreads();
        // 10 threads combine the 16 wave partials, publish v = q / colsum
        if (tid < 10) {
            float s = 0.f;
#pragma unroll
            for (int q = 0; q < 16; q++) s += wred[q][tid];
            ((float*)vbc4)[tid] = 0.1f * frcp(fmaxf(s, 1e-30f));
        }
        __syncthreads();
        {   // broadcast v via 3 x ds_read_b128
            float4 a = vbc4[0], b = vbc4[1], c = vbc4[2];
            vv[0]=a.x; vv[1]=a.y; vv[2]=a.z; vv[3]=a.w;
            vv[4]=b.x; vv[5]=b.y; vv[6]=b.z; vv[7]=b.w;
            vv[8]=c.x; vv[9]=c.y;
        }
        // row update: u = p / (K v); no NND mask — invalid rows have K==0,
        // so u stays finite (fmax guard) and contributes 0 next half-iter.
#pragma unroll
        for (int r = 0; r < SKR; r++) {
            float R = 0.f;
#pragma unroll
            for (int j = 0; j < 10; j++) R = fmaf(Kf[r][j], vv[j], R);
            u[r] = 2e-4f * frcp(fmaxf(R, 1e-30f));
        }
    }

    // T += step * (u K v - T)   (padded rows: 3 loads / 3 stores)
#pragma unroll
    for (int r = 0; r < SKR; r++) {
        int i = tid + r * SKB;
        if (i < NND) {
            float ur = u[r];
            float4* Tr4 = (float4*)(Tt + (size_t)i * ROWP);
            float4 t0 = Tr4[0], t1 = Tr4[1];
            float2 t2v = ((float2*)Tr4)[4];
            t0.x += step * (ur * Kf[r][0] * vv[0] - t0.x);
            t0.y += step * (ur * Kf[r][1] * vv[1] - t0.y);
            t0.z += step * (ur * Kf[r][2] * vv[2] - t0.z);
            t0.w += step * (ur * Kf[r][3] * vv[3] - t0.w);
            t1.x += step * (ur * Kf[r][4] * vv[4] - t1.x);
            t1.y += step * (ur * Kf[r][5] * vv[5] - t1.y);
            t1.z += step * (ur * Kf[r][6] * vv[6] - t1.z);
            t1.w += step * (ur * Kf[r][7] * vv[7] - t1.w);
            t2v.x += step * (ur * Kf[r][8] * vv[8] - t2v.x);
            t2v.y += step * (ur * Kf[r][9] * vv[9] - t2v.y);
            Tr4[0] = t0; Tr4[1] = t1;
            ((float2*)Tr4)[4] = t2v;
        }
    }
}

// ---------------- final distance + fused linear head ----------------

__global__ __launch_bounds__(256) void k_final(const float* __restrict__ T, const float* __restrict__ Mm,
                                               const float* __restrict__ c1row, const float* __restrict__ c2row,
                                               const float* __restrict__ tpl,
                                               const int* __restrict__ rpS, const int* __restrict__ csrD,
                                               double* __restrict__ dd, int* __restrict__ done,
                                               const float* __restrict__ Wlin,
                                               const float* __restrict__ blin,
                                               float* __restrict__ out) {
    int t = blockIdx.y;
    int tid = threadIdx.x;
    __shared__ float tC2[100];
    if (tid < 100) tC2[tid] = 2.f * tpl[t * 100 + tid];
    __syncthreads();
    int i = blockIdx.x * 256 + tid;
    double msum = 0.0, tsum = 0.0;
    if (i < NND) {
        const float* Tt = T + (size_t)t * NMATP;
        float4 A0 = make_float4(0.f,0.f,0.f,0.f);
        float4 A1 = make_float4(0.f,0.f,0.f,0.f);
        float2 A2 = make_float2(0.f,0.f);
        int e0 = rpS[i], e1 = rpS[i + 1];
        int e = e0;
        for (; e + 3 < e1; e += 4) {
            int ka = csrD[e], kb = csrD[e+1], kc = csrD[e+2], kd = csrD[e+3];
            const float4* Ta = (const float4*)(Tt + (size_t)ka * ROWP);
            const float4* Tb = (const float4*)(Tt + (size_t)kb * ROWP);
            const float4* Tc = (const float4*)(Tt + (size_t)kc * ROWP);
            const float4* Td = (const float4*)(Tt + (size_t)kd * ROWP);
            float4 a0 = Ta[0], a1 = Ta[1]; float2 a2 = ((const float2*)Ta)[4];
            float4 b0 = Tb[0], b1 = Tb[1]; float2 b2v = ((const float2*)Tb)[4];
            float4 c0 = Tc[0], c1 = Tc[1]; float2 c2v = ((const float2*)Tc)[4];
            float4 d0 = Td[0], d1 = Td[1]; float2 d2v = ((const float2*)Td)[4];
            A0.x += (a0.x + b0.x) + (c0.x + d0.x);
            A0.y += (a0.y + b0.y) + (c0.y + d0.y);
            A0.z += (a0.z + b0.z) + (c0.z + d0.z);
            A0.w += (a0.w + b0.w) + (c0.w + d0.w);
            A1.x += (a1.x + b1.x) + (c1.x + d1.x);
            A1.y += (a1.y + b1.y) + (c1.y + d1.y);
            A1.z += (a1.z + b1.z) + (c1.z + d1.z);
            A1.w += (a1.w + b1.w) + (c1.w + d1.w);
            A2.x += (a2.x + b2v.x) + (c2v.x + d2v.x);
            A2.y += (a2.y + b2v.y) + (c2v.y + d2v.y);
        }
        for (; e < e1; e++) {
            int ka = csrD[e];
            const float4* Ta = (const float4*)(Tt + (size_t)ka * ROWP);
            float4 a0 = Ta[0], a1 = Ta[1];
            float2 a2 = ((const float2*)Ta)[4];
            A0.x += a0.x; A0.y += a0.y; A0.z += a0.z; A0.w += a0.w;
            A1.x += a1.x; A1.y += a1.y; A1.z += a1.z; A1.w += a1.w;
            A2.x += a2.x; A2.y += a2.y;
        }
        float L[10] = {A0.x, A0.y, A0.z, A0.w, A1.x, A1.y, A1.z, A1.w, A2.x, A2.y};
        const float4* Mt4 = (const float4*)(Mm + (size_t)t * NMATP + (size_t)i * ROWP);
        float4 m0 = Mt4[0], m1 = Mt4[1];
        float2 m2 = ((const float2*)Mt4)[4];
        float m[10] = {m0.x, m0.y, m0.z, m0.w, m1.x, m1.y, m1.z, m1.w, m2.x, m2.y};
        const float4* Ti4 = (const float4*)(Tt + (size_t)i * ROWP);
        float4 tv0 = Ti4[0], tv1 = Ti4[1];
        float2 tv2 = ((const float2*)Ti4)[4];
        float Tv[10] = {tv0.x, tv0.y, tv0.z, tv0.w, tv1.x, tv1.y, tv1.z, tv1.w, tv2.x, tv2.y};
        float c1 = c1row[i];
#pragma unroll
        for (int j = 0; j < MT; j++) {
            float s = 0.f;
#pragma unroll
            for (int k = 0; k < MT; k++) s = fmaf(L[k], tC2[j * 10 + k], s);
            float ts = c1 + c2row[t * 10 + j] - s;
            msum += (double)(m[j] * Tv[j]);
            tsum += (double)(ts * Tv[j]);
        }
    }
    __shared__ double r1[256], r2[256];
    r1[tid] = msum; r2[tid] = tsum; __syncthreads();
    for (int off = 128; off > 0; off >>= 1) {
        if (tid < off) { r1[tid] += r1[tid + off]; r2[tid] += r2[tid + off]; }
        __syncthreads();
    }
    if (tid == 0) {
        atomicAdd(&dd[t * 2], r1[0]);
        atomicAdd(&dd[t * 2 + 1], r2[0]);
        __threadfence();
        int prev = atomicAdd(done, 1);
        if (prev == 20 * NT - 1) {           // last block computes the head
            __threadfence();
            float ds[NT];
#pragma unroll
            for (int k = 0; k < NT; k++) {
                unsigned long long b0 = __hip_atomic_load((unsigned long long*)&dd[2*k],
                                        __ATOMIC_RELAXED, __HIP_MEMORY_SCOPE_AGENT);
                unsigned long long b1 = __hip_atomic_load((unsigned long long*)&dd[2*k+1],
                                        __ATOMIC_RELAXED, __HIP_MEMORY_SCOPE_AGENT);
                ds[k] = 0.5f * (float)(__longlong_as_double(b0) + __longlong_as_double(b1));
            }
#pragma unroll
            for (int c = 0; c < NC; c++) {
                float o = blin[c];
#pragma unroll
                for (int k = 0; k < NT; k++) o = fmaf(ds[k], Wlin[k * NC + c], o);
                out[c] = o;
            }
        }
    }
}

// ---------------- host ----------------

extern "C" void kernel_launch(void* const* d_in, const int* in_sizes, int n_in,
                              void* d_out, int out_size, void* d_ws, size_t ws_size,
                              hipStream_t stream) {
    const float* x    = (const float*)d_in[0];
    const int*   ei   = (const int*)d_in[1];
    const int*   src  = ei;
    const int*   dst  = ei + NE;
    const float* W1   = (const float*)d_in[2];
    const float* b1   = (const float*)d_in[3];
    const float* W2   = (const float*)d_in[4];
    const float* b2   = (const float*)d_in[5];
    const float* tpl  = (const float*)d_in[6];
    const float* tplF = (const float*)d_in[7];
    const float* Wlin = (const float*)d_in[8];
    const float* blin = (const float*)d_in[9];
    float* out = (float*)d_out;

    char* w = (char*)d_ws;
    size_t off = 0;
    auto alloc = [&](size_t b) -> char* {
        off = (off + 255) & ~(size_t)255;
        char* p = w + off; off += b; return p;
    };
    float* bufA = (float*)alloc((size_t)NND * NH * 4);   // aggX / t2 (reused)
    float* bufB = (float*)alloc((size_t)NND * NH * 4);   // h1
    float* Mm   = (float*)alloc((size_t)NT * NMATP * 4); // padded (stride 12)
    float* T    = (float*)alloc((size_t)NT * NMATP * 4); // padded (stride 12)
    float* G    = (float*)alloc((size_t)NT * NMAT * 4);  // unpadded (stride 10)
    float* pmax = (float*)alloc((size_t)NT * NND * 4);   // fully written by k_fuse
    // --- zero group (one memset, bitmap included) ---
    int* cntD = (int*)alloc((size_t)NND * 4);
    int* cntS = (int*)alloc((size_t)NND * 4);
    int* cur1 = (int*)alloc((size_t)NND * 4);
    int* cur2 = (int*)alloc((size_t)NND * 4);
    double* dd = (double*)alloc((size_t)NT * 2 * 8);
    int* done = (int*)alloc(4);
    unsigned* scaleArr = (unsigned*)alloc((size_t)CG_ITERS * NT * 4);
    unsigned* bitmap = (unsigned*)alloc((size_t)781250 * 4);
    char* zend = w + off;
    // --- rest ---
    int* rpD  = (int*)alloc((size_t)(NND + 1) * 4);
    int* rpS  = (int*)alloc((size_t)(NND + 1) * 4);
    int* csrS = (int*)alloc((size_t)NE * 4);
    float* csrC = (float*)alloc((size_t)NE * 4);
    int* csrD2 = (int*)alloc((size_t)NE * 4);
    unsigned char* keep = (unsigned char*)alloc((size_t)NE);
    float* dinv  = (float*)alloc((size_t)NND * 4);
    float* c1row = (float*)alloc((size_t)NND * 4);
    float* c2row = (float*)alloc((size_t)100 * 4);
    float* rsT   = (float*)alloc((size_t)100 * 4);

    hipMemsetAsync(cntD, 0, (size_t)(zend - (char*)cntD), stream);

    // graph prep (merged passes)
    k_edge1<<<625, 256, 0, stream>>>(src, dst, cntD, bitmap, cntS, keep);
    k_exscan2<<<3, 1024, 0, stream>>>(cntD, rpD, dinv, cntS, rpS, c1row, tpl, c2row, rsT);
    k_scatter2<<<625, 256, 0, stream>>>(src, dst, keep, rpD, cur1, csrS, csrC, dinv,
                                        rpS, cur2, csrD2);

    // GCN: layer1 = relu((agg x) @ W1 + b1); layer2 = agg(h1 @ W2) + b2 (agg in k_fuse)
    k_aggregate<<<625, 256, 0, stream>>>((const float4*)x, (float4*)bufA,
                                         rpD, csrS, csrC, dinv);
    k_gemm<<<dim3(NH / 64, (NND + 63) / 64), 256, 0, stream>>>(bufA, W1, bufB, NND, NH, NF, b1, 1);
    k_gemm<<<dim3(NF / 64, (NND + 63) / 64), 256, 0, stream>>>(bufB, W2, bufA, NND, NF, NH, nullptr, 0);

    // fused: aggregate2 + M + T-init + closed-form grad0 + per-node scale maxes
    k_fuse<<<NND, 128, 0, stream>>>(bufA, b2, rpD, csrS, csrC, dinv, tplF,
                                    c1row, cntS, c2row, rsT, Mm, G, T, pmax);

    // conditional gradient loop; iter 0's gradient already in G (k_fuse)
    for (int t = 0; t < CG_ITERS; t++) {
        unsigned* sb = scaleArr + t * NT;
        if (t > 0)
            k_grad<<<dim3(20, NT), 256, 0, stream>>>(T, Mm, c1row, c2row, tpl, rpS, csrD2, G, sb);
        float step = 2.f / (float)(t + 2);
        k_sinkhorn<<<NT, SKB, 0, stream>>>(G, sb, (t == 0) ? pmax : nullptr, T, step);
    }

    // final distances + fused linear head (last block via done-counter)
    k_final<<<dim3(20, NT), 256, 0, stream>>>(T, Mm, c1row, c2row, tpl, rpS, csrD2,
                                              dd, done, Wlin, blin, out);
}

// Round 14
// 615.881 us; speedup vs baseline: 1.0238x; 1.0238x over previous
//
#include <hip/hip_runtime.h>
#include <cstdint>

#define NND 5000
#define NE 160000
#define NF 128
#define NH 256
#define NT 10
#define MT 10
#define NC 8
#define NMAT (NND*MT)      // G: unpadded stride 10 (sinkhorn-friendly)
#define ROWP 12            // T/M: padded row stride (48 B, float4-aligned gathers)
#define NMATP (NND*ROWP)
#define CG_ITERS 5
#define SINK_IT 30

// ---------------- wave-level f32 reductions (DPP, VALU pipe) ----------------
#if __has_builtin(__builtin_amdgcn_update_dpp)
#define DPP_ADD(x, ctrl, rmask) \
    ((x) + __int_as_float(__builtin_amdgcn_update_dpp(0, __float_as_int(x), (ctrl), (rmask), 0xf, true)))
#define DPP_MAX(x, ctrl, rmask) \
    fmaxf((x), __int_as_float(__builtin_amdgcn_update_dpp(0, __float_as_int(x), (ctrl), (rmask), 0xf, true)))
__device__ __forceinline__ float wave_sum63(float x) {
    x = DPP_ADD(x, 0x111, 0xf);   // row_shr:1
    x = DPP_ADD(x, 0x112, 0xf);   // row_shr:2
    x = DPP_ADD(x, 0x114, 0xf);   // row_shr:4
    x = DPP_ADD(x, 0x118, 0xf);   // row_shr:8
    x = DPP_ADD(x, 0x142, 0xa);   // row_bcast:15 -> rows 1,3
    x = DPP_ADD(x, 0x143, 0xc);   // row_bcast:31 -> rows 2,3
    return x;                      // lane 63 = full 64-lane sum
}
// valid for x >= 0 (identity 0 from bound_ctrl)
__device__ __forceinline__ float wave_max63(float x) {
    x = DPP_MAX(x, 0x111, 0xf);
    x = DPP_MAX(x, 0x112, 0xf);
    x = DPP_MAX(x, 0x114, 0xf);
    x = DPP_MAX(x, 0x118, 0xf);
    x = DPP_MAX(x, 0x142, 0xa);
    x = DPP_MAX(x, 0x143, 0xc);
    return x;
}
#else
__device__ __forceinline__ float wave_sum63(float x) {
#pragma unroll
    for (int off = 32; off; off >>= 1) x += __shfl_xor(x, off);
    return x;
}
__device__ __forceinline__ float wave_max63(float x) {
#pragma unroll
    for (int off = 32; off; off >>= 1) x = fmaxf(x, __shfl_xor(x, off));
    return x;
}
#endif

__device__ __forceinline__ float frcp(float x) {
#if __has_builtin(__builtin_amdgcn_rcpf)
    return __builtin_amdgcn_rcpf(x);   // v_rcp_f32, ~1 ulp
#else
    return 1.f / x;
#endif
}

// ---------------- graph prep (merged) ----------------

__global__ void k_edge1(const int* __restrict__ src, const int* __restrict__ dst,
                        int* __restrict__ cntD, unsigned* __restrict__ bitmap,
                        int* __restrict__ cntS, unsigned char* __restrict__ keep) {
    for (int e = blockIdx.x*blockDim.x + threadIdx.x; e < NE; e += gridDim.x*blockDim.x) {
        int s = src[e], d = dst[e];
        atomicAdd(&cntD[d], 1);
        int key = s * NND + d;
        unsigned bit = 1u << (key & 31);
        unsigned old = atomicOr(&bitmap[key >> 5], bit);
        if (!(old & bit)) { keep[e] = 1; atomicAdd(&cntS[s], 1); }
        else keep[e] = 0;
    }
}

// block 0: cntD -> rpD (+ dinv); block 1: cntS -> rpS (+ c1row);
// block 2: c2row + template row sums (for closed-form first gradient)
__global__ void k_exscan2(const int* __restrict__ cntD, int* __restrict__ rpD,
                          float* __restrict__ dinv,
                          const int* __restrict__ cntS, int* __restrict__ rpS,
                          float* __restrict__ c1row,
                          const float* __restrict__ tpl, float* __restrict__ c2row,
                          float* __restrict__ rsT) {
    const int T = 1024;
    int tid = threadIdx.x;
    if (blockIdx.x == 2) {
        if (tid < NT * MT) {
            int t = tid / MT, j = tid % MT;
            float s = 0.f, rs = 0.f;
            for (int k = 0; k < MT; k++) {
                float v = tpl[t * 100 + j * 10 + k];
                s += v * v; rs += v;
            }
            c2row[tid] = s * (1.f / MT);
            rsT[tid] = rs;
        }
        return;
    }
    const int* cnt = blockIdx.x ? cntS : cntD;
    int* rp = blockIdx.x ? rpS : rpD;
    int C = (NND + T - 1) / T;
    int begin = tid * C, end = begin + C; if (end > NND) end = NND; if (begin > NND) begin = NND;
    int s = 0;
    for (int i = begin; i < end; i++) s += cnt[i];
    __shared__ int part[1024];
    part[tid] = s; __syncthreads();
    for (int off = 1; off < T; off <<= 1) {
        int v = (tid >= off) ? part[tid - off] : 0;
        __syncthreads();
        part[tid] += v;
        __syncthreads();
    }
    int run = part[tid] - s;   // exclusive
    for (int i = begin; i < end; i++) { rp[i] = run; run += cnt[i]; }
    if (tid == T - 1) rp[NND] = part[T - 1];
    if (blockIdx.x == 0)
        for (int i = begin; i < end; i++) dinv[i] = rsqrtf((float)(cnt[i] + 1));
    else
        for (int i = begin; i < end; i++) c1row[i] = (float)cnt[i] * (1.f / NND);
}

__global__ void k_scatter2(const int* __restrict__ src, const int* __restrict__ dst,
                           const unsigned char* __restrict__ keep,
                           const int* __restrict__ rpD, int* __restrict__ cur1,
                           int* __restrict__ csrS, float* __restrict__ csrC,
                           const float* __restrict__ dinv,
                           const int* __restrict__ rpS, int* __restrict__ cur2,
                           int* __restrict__ csrD) {
    for (int e = blockIdx.x*blockDim.x + threadIdx.x; e < NE; e += gridDim.x*blockDim.x) {
        int s = src[e], d = dst[e];
        int pos = rpD[d] + atomicAdd(&cur1[d], 1);
        csrS[pos] = s;
        csrC[pos] = dinv[s] * dinv[d];
        if (keep[e]) {
            int p2 = rpS[s] + atomicAdd(&cur2[s], 1);
            csrD[p2] = d;
        }
    }
}

// ---------------- GCN ----------------
// GCN layer = agg(x @ W) + b; aggregation is linear in features, so layer 1
// uses (agg x) @ W + b (aggregate 128-dim rows instead of 256-dim).

__global__ __launch_bounds__(256) void k_gemm(const float* __restrict__ A,
                                              const float* __restrict__ B,
                                              float* __restrict__ C, int M, int N, int K,
                                              const float* __restrict__ bias, int relu) {
    const int BM = 64, BN = 64, BK = 32;   // BK=32: half the barriers of BK=16
    __shared__ float As[BK][BM + 4];       // rows 272B, 16B-aligned
    __shared__ float Bs[BK][BN];
    int tid = threadIdx.x;
    int row0 = blockIdx.y * BM, col0 = blockIdx.x * BN;
    int tx = tid % 16, ty = tid / 16;
    float acc[4][4] = {};
    for (int k0 = 0; k0 < K; k0 += BK) {
#pragma unroll
        for (int l = 0; l < 8; l++) {
            int idx = tid + l * 256;
            int r = idx / BK, kk = idx % BK;
            int gr = row0 + r;
            As[kk][r] = (gr < M) ? A[(size_t)gr * K + k0 + kk] : 0.f;
        }
#pragma unroll
        for (int l = 0; l < 8; l++) {
            int idx = tid + l * 256;
            int kk = idx / BN, c = idx % BN;
            Bs[kk][c] = B[(size_t)(k0 + kk) * N + col0 + c];
        }
        __syncthreads();
#pragma unroll
        for (int kk = 0; kk < BK; kk++) {
            float a[4], b[4];
#pragma unroll
            for (int i = 0; i < 4; i++) a[i] = As[kk][ty * 4 + i];
#pragma unroll
            for (int j = 0; j < 4; j++) b[j] = Bs[kk][tx * 4 + j];
#pragma unroll
            for (int i = 0; i < 4; i++)
#pragma unroll
                for (int j = 0; j < 4; j++) acc[i][j] += a[i] * b[j];
        }
        __syncthreads();
    }
#pragma unroll
    for (int i = 0; i < 4; i++) {
        int gr = row0 + ty * 4 + i;
        if (gr < M) {
#pragma unroll
            for (int j = 0; j < 4; j++) {
                int gc = col0 + tx * 4 + j;
                float o = acc[i][j];
                if (bias) o += bias[gc];
                if (relu) o = fmaxf(o, 0.f);
                C[(size_t)gr * N + gc] = o;
            }
        }
    }
}

// layer-1 aggregation over 128-dim rows: 8 nodes/256-block, 32 lanes x float4
// 4-way unrolled edge loop (four independent gather chains)
__global__ __launch_bounds__(256) void k_aggregate(const float4* __restrict__ hin4,
                            float4* __restrict__ hout4, const int* __restrict__ rp,
                            const int* __restrict__ csrS, const float* __restrict__ csrC,
                            const float* __restrict__ dinv) {
    int v = blockIdx.x * 8 + (threadIdx.x >> 5);
    int l = threadIdx.x & 31;
    float dv = dinv[v];
    float sc = dv * dv;
    float4 a = hin4[(size_t)v * 32 + l];
    float4 acc = make_float4(a.x * sc, a.y * sc, a.z * sc, a.w * sc);
    int e0 = rp[v], e1 = rp[v + 1];
    int e = e0;
    for (; e + 3 < e1; e += 4) {
        int s0 = csrS[e],   s1 = csrS[e+1], s2 = csrS[e+2], s3 = csrS[e+3];
        float c0 = csrC[e], c1 = csrC[e+1], c2 = csrC[e+2], c3 = csrC[e+3];
        float4 h0 = hin4[(size_t)s0 * 32 + l];
        float4 h1 = hin4[(size_t)s1 * 32 + l];
        float4 h2 = hin4[(size_t)s2 * 32 + l];
        float4 h3 = hin4[(size_t)s3 * 32 + l];
        acc.x = fmaf(h0.x, c0, acc.x); acc.y = fmaf(h0.y, c0, acc.y);
        acc.z = fmaf(h0.z, c0, acc.z); acc.w = fmaf(h0.w, c0, acc.w);
        acc.x = fmaf(h1.x, c1, acc.x); acc.y = fmaf(h1.y, c1, acc.y);
        acc.z = fmaf(h1.z, c1, acc.z); acc.w = fmaf(h1.w, c1, acc.w);
        acc.x = fmaf(h2.x, c2, acc.x); acc.y = fmaf(h2.y, c2, acc.y);
        acc.z = fmaf(h2.z, c2, acc.z); acc.w = fmaf(h2.w, c2, acc.w);
        acc.x = fmaf(h3.x, c3, acc.x); acc.y = fmaf(h3.y, c3, acc.y);
        acc.z = fmaf(h3.z, c3, acc.z); acc.w = fmaf(h3.w, c3, acc.w);
    }
    for (; e < e1; e++) {
        int s0 = csrS[e]; float c0 = csrC[e];
        float4 h0 = hin4[(size_t)s0 * 32 + l];
        acc.x = fmaf(h0.x, c0, acc.x); acc.y = fmaf(h0.y, c0, acc.y);
        acc.z = fmaf(h0.z, c0, acc.z); acc.w = fmaf(h0.w, c0, acc.w);
    }
    hout4[(size_t)v * 32 + l] = acc;
}

// ---------------- fused: aggregate2 + M + T-init + closed-form grad0 ----------------
// One block per node (128 threads). Aggregation: 4 edge-quads x 32 lanes x float4
// (16B/lane coalesced, 4 independent chains), LDS-combine of partial rows.
// h2 row stays in LDS; M/T padded, G unpadded.
__global__ __launch_bounds__(128) void k_fuse(const float* __restrict__ t2,
                    const float* __restrict__ b2,
                    const int* __restrict__ rp, const int* __restrict__ csrS,
                    const float* __restrict__ csrC, const float* __restrict__ dinv,
                    const float* __restrict__ tplF,
                    const float* __restrict__ c1row, const int* __restrict__ cntS,
                    const float* __restrict__ c2row, const float* __restrict__ rsT,
                    float* __restrict__ Mm, float* __restrict__ G,
                    float* __restrict__ T, float* __restrict__ pmax) {
    int i = blockIdx.x;
    int tid = threadIdx.x;
    int lane = tid & 63, w = tid >> 6;
    int q = tid >> 5, l = tid & 31;          // edge-quad, feature-f4 lane
    __shared__ float4 sacc[4][32];
    __shared__ float hrow[NF];
    __shared__ float part[2];
    __shared__ float sMax[112];
    const float4* t24 = (const float4*)t2;
    // phase 1: gather neighbor rows, 4 edges in parallel (q = edge slot)
    float4 f = make_float4(0.f, 0.f, 0.f, 0.f);
    int e0 = rp[i], e1 = rp[i + 1];
    for (int e = e0 + q; e < e1; e += 4) {
        int s = csrS[e];
        float c = csrC[e];
        float4 h = t24[(size_t)s * 32 + l];
        f.x = fmaf(h.x, c, f.x); f.y = fmaf(h.y, c, f.y);
        f.z = fmaf(h.z, c, f.z); f.w = fmaf(h.w, c, f.w);
    }
    sacc[q][l] = f;
    __syncthreads();
    // phase 2: combine quads + self-loop + bias -> hrow (32 lanes)
    if (tid < 32) {
        float4 r0 = sacc[0][tid], r1 = sacc[1][tid], r2 = sacc[2][tid], r3 = sacc[3][tid];
        float dv = dinv[i];
        float sc = dv * dv;
        float4 sv = t24[(size_t)i * 32 + tid];
        float4 bb = ((const float4*)b2)[tid];
        float4 o;
        o.x = (r0.x + r1.x) + (r2.x + r3.x) + sv.x * sc + bb.x;
        o.y = (r0.y + r1.y) + (r2.y + r3.y) + sv.y * sc + bb.y;
        o.z = (r0.z + r1.z) + (r2.z + r3.z) + sv.z * sc + bb.z;
        o.w = (r0.w + r1.w) + (r2.w + r3.w) + sv.w * sc + bb.w;
        ((float4*)hrow)[tid] = o;
    }
    __syncthreads();
    float hv = hrow[tid];
    float ps = wave_sum63(hv * hv);
    if (lane == 63) part[w] = ps;
    __syncthreads();
    float sx = part[0] + part[1];
    int c = tid;
    if (c < NT * MT) {
        const float4* Fc = (const float4*)(tplF + (size_t)c * NF);
        const float4* hr = (const float4*)hrow;
        float dot = 0.f, nrm = 0.f;
#pragma unroll 8
        for (int ff = 0; ff < NF / 4; ff++) {
            float4 fv = Fc[ff];
            float4 hq = hr[ff];
            dot = fmaf(hq.x, fv.x, dot); dot = fmaf(hq.y, fv.y, dot);
            dot = fmaf(hq.z, fv.z, dot); dot = fmaf(hq.w, fv.w, dot);
            nrm = fmaf(fv.x, fv.x, nrm); nrm = fmaf(fv.y, fv.y, nrm);
            nrm = fmaf(fv.z, fv.z, nrm); nrm = fmaf(fv.w, fv.w, nrm);
        }
        float m = sx + nrm - 2.f * dot;
        int t = c / MT, j = c % MT;
        size_t baseP = (size_t)t * NMATP + (size_t)i * ROWP + j;   // padded (M, T)
        Mm[baseP] = m;
        T[baseP] = 1.f / (float)NMAT;
        // closed-form first gradient (T0 uniform) -> unpadded G
        float g = 0.5f * m + c1row[i] + c2row[c]
                - ((float)cntS[i] * (1.f / NMAT)) * (2.f * rsT[c]);
        G[(size_t)t * NMAT + (size_t)i * MT + j] = g;
        sMax[c] = fabsf(g);
    }
    __syncthreads();
    if (tid < NT) {
        float m = sMax[tid * 10];
#pragma unroll
        for (int k = 1; k < 10; k++) m = fmaxf(m, sMax[tid * 10 + k]);
        pmax[(size_t)tid * NND + i] = m;
    }
}

// ---------------- CG gradient (t >= 1) — padded T gather (4-way), unpadded G write ----------------

__global__ __launch_bounds__(256) void k_grad(const float* __restrict__ T, const float* __restrict__ Mm,
                                              const float* __restrict__ c1row, const float* __restrict__ c2row,
                                              const float* __restrict__ tpl,
                                              const int* __restrict__ rpS, const int* __restrict__ csrD,
                                              float* __restrict__ G, unsigned* __restrict__ scaleBits) {
    int t = blockIdx.y;
    int tid = threadIdx.x;
    __shared__ float tC2[100];
    if (tid < 100) tC2[tid] = 2.f * tpl[t * 100 + tid];
    __syncthreads();
    int i = blockIdx.x * 256 + tid;
    float amax = 0.f;
    if (i < NND) {
        const float* Tt = T + (size_t)t * NMATP;
        float4 A0 = make_float4(0.f,0.f,0.f,0.f);
        float4 A1 = make_float4(0.f,0.f,0.f,0.f);
        float2 A2 = make_float2(0.f,0.f);
        int e0 = rpS[i], e1 = rpS[i + 1];
        int e = e0;
        for (; e + 3 < e1; e += 4) {   // four independent gather chains
            int ka = csrD[e], kb = csrD[e+1], kc = csrD[e+2], kd = csrD[e+3];
            const float4* Ta = (const float4*)(Tt + (size_t)ka * ROWP);
            const float4* Tb = (const float4*)(Tt + (size_t)kb * ROWP);
            const float4* Tc = (const float4*)(Tt + (size_t)kc * ROWP);
            const float4* Td = (const float4*)(Tt + (size_t)kd * ROWP);
            float4 a0 = Ta[0], a1 = Ta[1]; float2 a2 = ((const float2*)Ta)[4];
            float4 b0 = Tb[0], b1 = Tb[1]; float2 b2v = ((const float2*)Tb)[4];
            float4 c0 = Tc[0], c1 = Tc[1]; float2 c2v = ((const float2*)Tc)[4];
            float4 d0 = Td[0], d1 = Td[1]; float2 d2v = ((const float2*)Td)[4];
            A0.x += (a0.x + b0.x) + (c0.x + d0.x);
            A0.y += (a0.y + b0.y) + (c0.y + d0.y);
            A0.z += (a0.z + b0.z) + (c0.z + d0.z);
            A0.w += (a0.w + b0.w) + (c0.w + d0.w);
            A1.x += (a1.x + b1.x) + (c1.x + d1.x);
            A1.y += (a1.y + b1.y) + (c1.y + d1.y);
            A1.z += (a1.z + b1.z) + (c1.z + d1.z);
            A1.w += (a1.w + b1.w) + (c1.w + d1.w);
            A2.x += (a2.x + b2v.x) + (c2v.x + d2v.x);
            A2.y += (a2.y + b2v.y) + (c2v.y + d2v.y);
        }
        for (; e < e1; e++) {
            int ka = csrD[e];
            const float4* Ta = (const float4*)(Tt + (size_t)ka * ROWP);
            float4 a0 = Ta[0], a1 = Ta[1];
            float2 a2 = ((const float2*)Ta)[4];
            A0.x += a0.x; A0.y += a0.y; A0.z += a0.z; A0.w += a0.w;
            A1.x += a1.x; A1.y += a1.y; A1.z += a1.z; A1.w += a1.w;
            A2.x += a2.x; A2.y += a2.y;
        }
        float L[10] = {A0.x, A0.y, A0.z, A0.w, A1.x, A1.y, A1.z, A1.w, A2.x, A2.y};
        const float4* Mt4 = (const float4*)(Mm + (size_t)t * NMATP + (size_t)i * ROWP);
        float4 m0 = Mt4[0], m1 = Mt4[1];
        float2 m2 = ((const float2*)Mt4)[4];
        float m[10] = {m0.x, m0.y, m0.z, m0.w, m1.x, m1.y, m1.z, m1.w, m2.x, m2.y};
        float c1 = c1row[i];
        float g[10];
#pragma unroll
        for (int j = 0; j < MT; j++) {
            float s = 0.f;
#pragma unroll
            for (int k = 0; k < MT; k++) s = fmaf(L[k], tC2[j * 10 + k], s);
            g[j] = 0.5f * m[j] + (c1 + c2row[t * 10 + j] - s);
            amax = fmaxf(amax, fabsf(g[j]));
        }
        float2* Gt2 = (float2*)(G + (size_t)t * NMAT + (size_t)i * MT);   // unpadded
#pragma unroll
        for (int h = 0; h < 5; h++) Gt2[h] = make_float2(g[2*h], g[2*h+1]);
    }
    __shared__ float red[256];
    red[tid] = amax; __syncthreads();
    for (int off = 128; off > 0; off >>= 1) {
        if (tid < off) red[tid] = fmaxf(red[tid], red[tid + off]);
        __syncthreads();
    }
    if (tid == 0) atomicMax(&scaleBits[t], __float_as_uint(red[0]));
}

// ---------------- sinkhorn (round-12 best-measured config) ----------------
// One block per template, 512 threads, 10 rows/thread, all-f32 scaling form.
// Empirical floor (rounds 4-13): seven structurally different variants
// (f64/f32, LDS-tree/DPP, serial/redundant combine, pk-FMA, 2 and 4 waves/SIMD)
// all measure 56.5-61.5 us — the per-iteration reduce->broadcast chain on one
// CU is the floor; cross-CU split costs ~10 us/generation (round 2).
__global__ __attribute__((amdgpu_flat_work_group_size(512, 512), amdgpu_waves_per_eu(2, 2)))
void k_sinkhorn(const float* __restrict__ G,
                const unsigned* __restrict__ scaleBits,
                const float* __restrict__ pmax,
                float* __restrict__ T, float step) {
    int t = blockIdx.x;
    int tid = threadIdx.x;
    int lane = tid & 63, w = tid >> 6;

    __shared__ float wred[8][10];
    __shared__ float4 vbc4[3];     // 12 floats, 16B-aligned for b128 broadcast reads
    __shared__ float scsh;

    float sc;
    if (pmax) {   // CG iter 0: reduce per-node maxes here (no atomics upstream)
        const float* pm = pmax + (size_t)t * NND;
        float m = 0.f;
        for (int k = tid; k < NND; k += 512) m = fmaxf(m, pm[k]);
        m = wave_max63(m);
        if (lane == 63) wred[w][0] = m;
        __syncthreads();
        if (tid == 0) {
            float mm = wred[0][0];
#pragma unroll
            for (int q = 1; q < 8; q++) mm = fmaxf(mm, wred[q][0]);
            scsh = mm;
        }
        __syncthreads();
        sc = scsh;
    } else {
        sc = __uint_as_float(scaleBits[t]);
    }
    float inv = -1.f / (0.02f * (sc + 1e-9f));
    const float* Gt = G + (size_t)t * NMAT;    // unpadded stride 10
    float* Tt = T + (size_t)t * NMATP;         // padded stride 12

    float Kf[10][10];
    float u[10];
#pragma unroll
    for (int r = 0; r < 10; r++) {
        int i = tid + r * 512;
        if (i < NND) {
            u[r] = 1.f;
            const float2* Gr = (const float2*)(Gt + (size_t)i * 10);
#pragma unroll
            for (int h = 0; h < 5; h++) {
                float2 g = Gr[h];
                Kf[r][2*h]   = __expf(g.x * inv);
                Kf[r][2*h+1] = __expf(g.y * inv);
            }
        } else {
            u[r] = 0.f;
#pragma unroll
            for (int j = 0; j < 10; j++) Kf[r][j] = 0.f;
        }
    }

    float vv[10];

    for (int it = 0; it < SINK_IT; it++) {
        // column partials over this thread's 10 rows
        float S[10];
#pragma unroll
        for (int j = 0; j < 10; j++) S[j] = 0.f;
#pragma unroll
        for (int r = 0; r < 10; r++) {
            float ur = u[r];
#pragma unroll
            for (int j = 0; j < 10; j++) S[j] = fmaf(Kf[r][j], ur, S[j]);
        }
        // DPP wave reduction (result in lane 63), lane 63 publishes
#pragma unroll
        for (int j = 0; j < 10; j++) {
            float s = wave_sum63(S[j]);
            if (lane == 63) wred[w][j] = s;
        }
        __syncthreads();
        // 10 threads combine the 8 wave partials, publish v = q / colsum
        if (tid < 10) {
            float s = 0.f;
#pragma unroll
            for (int q = 0; q < 8; q++) s += wred[q][tid];
            ((float*)vbc4)[tid] = 0.1f * frcp(fmaxf(s, 1e-30f));
        }
        __syncthreads();
        {   // broadcast v via 3 x ds_read_b128
            float4 a = vbc4[0], b = vbc4[1], c = vbc4[2];
            vv[0]=a.x; vv[1]=a.y; vv[2]=a.z; vv[3]=a.w;
            vv[4]=b.x; vv[5]=b.y; vv[6]=b.z; vv[7]=b.w;
            vv[8]=c.x; vv[9]=c.y;
        }
        // row update: u = p / (K v); no NND mask — invalid rows have K==0,
        // so u stays finite (fmax guard) and contributes 0 next half-iter.
#pragma unroll
        for (int r = 0; r < 10; r++) {
            float R = 0.f;
#pragma unroll
            for (int j = 0; j < 10; j++) R = fmaf(Kf[r][j], vv[j], R);
            u[r] = 2e-4f * frcp(fmaxf(R, 1e-30f));
        }
    }

    // T += step * (u K v - T)   (padded rows: 3 loads / 3 stores)
#pragma unroll
    for (int r = 0; r < 10; r++) {
        int i = tid + r * 512;
        if (i < NND) {
            float ur = u[r];
            float4* Tr4 = (float4*)(Tt + (size_t)i * ROWP);
            float4 t0 = Tr4[0], t1 = Tr4[1];
            float2 t2v = ((float2*)Tr4)[4];
            t0.x += step * (ur * Kf[r][0] * vv[0] - t0.x);
            t0.y += step * (ur * Kf[r][1] * vv[1] - t0.y);
            t0.z += step * (ur * Kf[r][2] * vv[2] - t0.z);
            t0.w += step * (ur * Kf[r][3] * vv[3] - t0.w);
            t1.x += step * (ur * Kf[r][4] * vv[4] - t1.x);
            t1.y += step * (ur * Kf[r][5] * vv[5] - t1.y);
            t1.z += step * (ur * Kf[r][6] * vv[6] - t1.z);
            t1.w += step * (ur * Kf[r][7] * vv[7] - t1.w);
            t2v.x += step * (ur * Kf[r][8] * vv[8] - t2v.x);
            t2v.y += step * (ur * Kf[r][9] * vv[9] - t2v.y);
            Tr4[0] = t0; Tr4[1] = t1;
            ((float2*)Tr4)[4] = t2v;
        }
    }
}

// ---------------- final distance + fused linear head ----------------

__global__ __launch_bounds__(256) void k_final(const float* __restrict__ T, const float* __restrict__ Mm,
                                               const float* __restrict__ c1row, const float* __restrict__ c2row,
                                               const float* __restrict__ tpl,
                                               const int* __restrict__ rpS, const int* __restrict__ csrD,
                                               double* __restrict__ dd, int* __restrict__ done,
                                               const float* __restrict__ Wlin,
                                               const float* __restrict__ blin,
                                               float* __restrict__ out) {
    int t = blockIdx.y;
    int tid = threadIdx.x;
    __shared__ float tC2[100];
    if (tid < 100) tC2[tid] = 2.f * tpl[t * 100 + tid];
    __syncthreads();
    int i = blockIdx.x * 256 + tid;
    double msum = 0.0, tsum = 0.0;
    if (i < NND) {
        const float* Tt = T + (size_t)t * NMATP;
        float4 A0 = make_float4(0.f,0.f,0.f,0.f);
        float4 A1 = make_float4(0.f,0.f,0.f,0.f);
        float2 A2 = make_float2(0.f,0.f);
        int e0 = rpS[i], e1 = rpS[i + 1];
        int e = e0;
        for (; e + 3 < e1; e += 4) {
            int ka = csrD[e], kb = csrD[e+1], kc = csrD[e+2], kd = csrD[e+3];
            const float4* Ta = (const float4*)(Tt + (size_t)ka * ROWP);
            const float4* Tb = (const float4*)(Tt + (size_t)kb * ROWP);
            const float4* Tc = (const float4*)(Tt + (size_t)kc * ROWP);
            const float4* Td = (const float4*)(Tt + (size_t)kd * ROWP);
            float4 a0 = Ta[0], a1 = Ta[1]; float2 a2 = ((const float2*)Ta)[4];
            float4 b0 = Tb[0], b1 = Tb[1]; float2 b2v = ((const float2*)Tb)[4];
            float4 c0 = Tc[0], c1 = Tc[1]; float2 c2v = ((const float2*)Tc)[4];
            float4 d0 = Td[0], d1 = Td[1]; float2 d2v = ((const float2*)Td)[4];
            A0.x += (a0.x + b0.x) + (c0.x + d0.x);
            A0.y += (a0.y + b0.y) + (c0.y + d0.y);
            A0.z += (a0.z + b0.z) + (c0.z + d0.z);
            A0.w += (a0.w + b0.w) + (c0.w + d0.w);
            A1.x += (a1.x + b1.x) + (c1.x + d1.x);
            A1.y += (a1.y + b1.y) + (c1.y + d1.y);
            A1.z += (a1.z + b1.z) + (c1.z + d1.z);
            A1.w += (a1.w + b1.w) + (c1.w + d1.w);
            A2.x += (a2.x + b2v.x) + (c2v.x + d2v.x);
            A2.y += (a2.y + b2v.y) + (c2v.y + d2v.y);
        }
        for (; e < e1; e++) {
            int ka = csrD[e];
            const float4* Ta = (const float4*)(Tt + (size_t)ka * ROWP);
            float4 a0 = Ta[0], a1 = Ta[1];
            float2 a2 = ((const float2*)Ta)[4];
            A0.x += a0.x; A0.y += a0.y; A0.z += a0.z; A0.w += a0.w;
            A1.x += a1.x; A1.y += a1.y; A1.z += a1.z; A1.w += a1.w;
            A2.x += a2.x; A2.y += a2.y;
        }
        float L[10] = {A0.x, A0.y, A0.z, A0.w, A1.x, A1.y, A1.z, A1.w, A2.x, A2.y};
        const float4* Mt4 = (const float4*)(Mm + (size_t)t * NMATP + (size_t)i * ROWP);
        float4 m0 = Mt4[0], m1 = Mt4[1];
        float2 m2 = ((const float2*)Mt4)[4];
        float m[10] = {m0.x, m0.y, m0.z, m0.w, m1.x, m1.y, m1.z, m1.w, m2.x, m2.y};
        const float4* Ti4 = (const float4*)(Tt + (size_t)i * ROWP);
        float4 tv0 = Ti4[0], tv1 = Ti4[1];
        float2 tv2 = ((const float2*)Ti4)[4];
        float Tv[10] = {tv0.x, tv0.y, tv0.z, tv0.w, tv1.x, tv1.y, tv1.z, tv1.w, tv2.x, tv2.y};
        float c1 = c1row[i];
#pragma unroll
        for (int j = 0; j < MT; j++) {
            float s = 0.f;
#pragma unroll
            for (int k = 0; k < MT; k++) s = fmaf(L[k], tC2[j * 10 + k], s);
            float ts = c1 + c2row[t * 10 + j] - s;
            msum += (double)(m[j] * Tv[j]);
            tsum += (double)(ts * Tv[j]);
        }
    }
    __shared__ double r1[256], r2[256];
    r1[tid] = msum; r2[tid] = tsum; __syncthreads();
    for (int off = 128; off > 0; off >>= 1) {
        if (tid < off) { r1[tid] += r1[tid + off]; r2[tid] += r2[tid + off]; }
        __syncthreads();
    }
    if (tid == 0) {
        atomicAdd(&dd[t * 2], r1[0]);
        atomicAdd(&dd[t * 2 + 1], r2[0]);
        __threadfence();
        int prev = atomicAdd(done, 1);
        if (prev == 20 * NT - 1) {           // last block computes the head
            __threadfence();
            float ds[NT];
#pragma unroll
            for (int k = 0; k < NT; k++) {
                unsigned long long b0 = __hip_atomic_load((unsigned long long*)&dd[2*k],
                                        __ATOMIC_RELAXED, __HIP_MEMORY_SCOPE_AGENT);
                unsigned long long b1 = __hip_atomic_load((unsigned long long*)&dd[2*k+1],
                                        __ATOMIC_RELAXED, __HIP_MEMORY_SCOPE_AGENT);
                ds[k] = 0.5f * (float)(__longlong_as_double(b0) + __longlong_as_double(b1));
            }
#pragma unroll
            for (int c = 0; c < NC; c++) {
                float o = blin[c];
#pragma unroll
                for (int k = 0; k < NT; k++) o = fmaf(ds[k], Wlin[k * NC + c], o);
                out[c] = o;
            }
        }
    }
}

// ---------------- host ----------------

extern "C" void kernel_launch(void* const* d_in, const int* in_sizes, int n_in,
                              void* d_out, int out_size, void* d_ws, size_t ws_size,
                              hipStream_t stream) {
    const float* x    = (const float*)d_in[0];
    const int*   ei   = (const int*)d_in[1];
    const int*   src  = ei;
    const int*   dst  = ei + NE;
    const float* W1   = (const float*)d_in[2];
    const float* b1   = (const float*)d_in[3];
    const float* W2   = (const float*)d_in[4];
    const float* b2   = (const float*)d_in[5];
    const float* tpl  = (const float*)d_in[6];
    const float* tplF = (const float*)d_in[7];
    const float* Wlin = (const float*)d_in[8];
    const float* blin = (const float*)d_in[9];
    float* out = (float*)d_out;

    char* w = (char*)d_ws;
    size_t off = 0;
    auto alloc = [&](size_t b) -> char* {
        off = (off + 255) & ~(size_t)255;
        char* p = w + off; off += b; return p;
    };
    float* bufA = (float*)alloc((size_t)NND * NH * 4);   // aggX / t2 (reused)
    float* bufB = (float*)alloc((size_t)NND * NH * 4);   // h1
    float* Mm   = (float*)alloc((size_t)NT * NMATP * 4); // padded (stride 12)
    float* T    = (float*)alloc((size_t)NT * NMATP * 4); // padded (stride 12)
    float* G    = (float*)alloc((size_t)NT * NMAT * 4);  // unpadded (stride 10)
    float* pmax = (float*)alloc((size_t)NT * NND * 4);   // fully written by k_fuse
    // --- zero group (one memset, bitmap included) ---
    int* cntD = (int*)alloc((size_t)NND * 4);
    int* cntS = (int*)alloc((size_t)NND * 4);
    int* cur1 = (int*)alloc((size_t)NND * 4);
    int* cur2 = (int*)alloc((size_t)NND * 4);
    double* dd = (double*)alloc((size_t)NT * 2 * 8);
    int* done = (int*)alloc(4);
    unsigned* scaleArr = (unsigned*)alloc((size_t)CG_ITERS * NT * 4);
    unsigned* bitmap = (unsigned*)alloc((size_t)781250 * 4);
    char* zend = w + off;
    // --- rest ---
    int* rpD  = (int*)alloc((size_t)(NND + 1) * 4);
    int* rpS  = (int*)alloc((size_t)(NND + 1) * 4);
    int* csrS = (int*)alloc((size_t)NE * 4);
    float* csrC = (float*)alloc((size_t)NE * 4);
    int* csrD2 = (int*)alloc((size_t)NE * 4);
    unsigned char* keep = (unsigned char*)alloc((size_t)NE);
    float* dinv  = (float*)alloc((size_t)NND * 4);
    float* c1row = (float*)alloc((size_t)NND * 4);
    float* c2row = (float*)alloc((size_t)100 * 4);
    float* rsT   = (float*)alloc((size_t)100 * 4);

    hipMemsetAsync(cntD, 0, (size_t)(zend - (char*)cntD), stream);

    // graph prep (merged passes)
    k_edge1<<<625, 256, 0, stream>>>(src, dst, cntD, bitmap, cntS, keep);
    k_exscan2<<<3, 1024, 0, stream>>>(cntD, rpD, dinv, cntS, rpS, c1row, tpl, c2row, rsT);
    k_scatter2<<<625, 256, 0, stream>>>(src, dst, keep, rpD, cur1, csrS, csrC, dinv,
                                        rpS, cur2, csrD2);

    // GCN: layer1 = relu((agg x) @ W1 + b1); layer2 = agg(h1 @ W2) + b2 (agg in k_fuse)
    k_aggregate<<<625, 256, 0, stream>>>((const float4*)x, (float4*)bufA,
                                         rpD, csrS, csrC, dinv);
    k_gemm<<<dim3(NH / 64, (NND + 63) / 64), 256, 0, stream>>>(bufA, W1, bufB, NND, NH, NF, b1, 1);
    k_gemm<<<dim3(NF / 64, (NND + 63) / 64), 256, 0, stream>>>(bufB, W2, bufA, NND, NF, NH, nullptr, 0);

    // fused: aggregate2 + M + T-init + closed-form grad0 + per-node scale maxes
    k_fuse<<<NND, 128, 0, stream>>>(bufA, b2, rpD, csrS, csrC, dinv, tplF,
                                    c1row, cntS, c2row, rsT, Mm, G, T, pmax);

    // conditional gradient loop; iter 0's gradient already in G (k_fuse)
    for (int t = 0; t < CG_ITERS; t++) {
        unsigned* sb = scaleArr + t * NT;
        if (t > 0)
            k_grad<<<dim3(20, NT), 256, 0, stream>>>(T, Mm, c1row, c2row, tpl, rpS, csrD2, G, sb);
        float step = 2.f / (float)(t + 2);
        k_sinkhorn<<<NT, 512, 0, stream>>>(G, sb, (t == 0) ? pmax : nullptr, T, step);
    }

    // final distances + fused linear head (last block via done-counter)
    k_final<<<dim3(20, NT), 256, 0, stream>>>(T, Mm, c1row, c2row, tpl, rpS, csrD2,
                                              dd, done, Wlin, blin, out);
}